// Round 1
// baseline (1197.638 us; speedup 1.0000x reference)
//
#include <hip/hip_runtime.h>
#include <math.h>

// Problem constants (hardcoded per reference)
constexpr int B = 2, T = 2048, C = 1024, H = 16, D = 64;
constexpr int M = B * T;          // 4096 rows for all projections
constexpr float SCALE = 0.125f;   // 1/sqrt(64)

// ---------------------------------------------------------------------------
// GEMM: out = A(M x 1024) @ W(1024 x 1024) + bias
// scatter=1: write to (B*H, T, 64) layout (head-split) for attention
// scatter=0: write row-major (M x 1024) (final output)
// Tile: BM=64, BN=64, BK=16; 256 threads; 4x4 per thread.
// ---------------------------------------------------------------------------
__global__ __launch_bounds__(256) void gemm_bias(
    const float* __restrict__ A, const float* __restrict__ W,
    const float* __restrict__ bias, float* __restrict__ out, int scatter)
{
    __shared__ float asT[16][68];   // [k][m], transposed A tile
    __shared__ float bs[16][68];    // [k][n]

    const int tid = threadIdx.x;
    const int ty = tid >> 4, tx = tid & 15;
    const int m0 = blockIdx.y * 64, n0 = blockIdx.x * 64;

    // loader mapping
    const int lm  = tid >> 2;          // 0..63  A row
    const int lk4 = (tid & 3) * 4;     // 0,4,8,12 k offset
    const int lkb = tid >> 4;          // 0..15  W row (k)
    const int ln4 = (tid & 15) * 4;    // 0..60  n offset

    const float* Ap = A + (size_t)(m0 + lm) * 1024 + lk4;
    const float* Wp = W + (size_t)lkb * 1024 + n0 + ln4;

    float acc[4][4] = {};

    for (int k0 = 0; k0 < 1024; k0 += 16) {
        float4 a4 = *(const float4*)(Ap + k0);
        float4 b4 = *(const float4*)(Wp + (size_t)k0 * 1024);
        __syncthreads();
        asT[lk4 + 0][lm] = a4.x;
        asT[lk4 + 1][lm] = a4.y;
        asT[lk4 + 2][lm] = a4.z;
        asT[lk4 + 3][lm] = a4.w;
        *(float4*)&bs[lkb][ln4] = b4;
        __syncthreads();
#pragma unroll
        for (int kk = 0; kk < 16; kk++) {
            float4 av = *(float4*)&asT[kk][ty * 4];
            float4 bv = *(float4*)&bs[kk][tx * 4];
            float a[4] = {av.x, av.y, av.z, av.w};
            float b[4] = {bv.x, bv.y, bv.z, bv.w};
#pragma unroll
            for (int i = 0; i < 4; i++)
#pragma unroll
                for (int j = 0; j < 4; j++)
                    acc[i][j] = fmaf(a[i], b[j], acc[i][j]);
        }
    }

    float4 bb = *(const float4*)(bias + n0 + tx * 4);
    const float badd[4] = {bb.x, bb.y, bb.z, bb.w};

#pragma unroll
    for (int i = 0; i < 4; i++) {
        float4 r;
        r.x = acc[i][0] + badd[0];
        r.y = acc[i][1] + badd[1];
        r.z = acc[i][2] + badd[2];
        r.w = acc[i][3] + badd[3];
        const int m_ = m0 + ty * 4 + i;
        if (scatter) {
            // row m -> (b, t); col n -> (h, d). n0 is 64-aligned -> h const per block.
            const int b_ = m_ >> 11;           // /T
            const int t_ = m_ & (T - 1);
            const int h_ = n0 >> 6;
            const int d_ = tx * 4;             // n0 & 63 == 0
            *(float4*)(out + (((size_t)(b_ * H + h_) * T + t_) * D) + d_) = r;
        } else {
            *(float4*)(out + (size_t)m_ * 1024 + n0 + tx * 4) = r;
        }
    }
}

// ---------------------------------------------------------------------------
// Flash-style attention. q,k,v in (B*H, T, 64) layout. Output written directly
// in (B, T, H*64) layout so the final projection is a plain GEMM.
// Block: 256 threads, one (bh, 64-query tile). K/V tiles of 64 keys.
// ---------------------------------------------------------------------------
__global__ __launch_bounds__(256) void attn(
    const float* __restrict__ q, const float* __restrict__ k,
    const float* __restrict__ v, float* __restrict__ o)
{
    __shared__ float qsT[64][68];   // [d][r], pre-scaled q
    __shared__ float kp[64][68];    // phase1: k^T [d][c]; phase3: p^T [c][r]
    __shared__ float vs[64][68];    // [c][dv]

    const int tid = threadIdx.x;
    const int ty = tid >> 4, tx = tid & 15;   // row-group / col-group
    const int qt = blockIdx.x;                // 0..31 query tile
    const int bh = blockIdx.y;                // 0..31

    const float* qb = q + ((size_t)bh * T + qt * 64) * D;
    const float* kb0 = k + (size_t)bh * T * D;
    const float* vb0 = v + (size_t)bh * T * D;

    // stage q tile transposed + scaled
#pragma unroll
    for (int it = 0; it < 4; it++) {
        int ff = tid + it * 256;
        int row = ff >> 4, c4 = (ff & 15) * 4;
        float4 x = *(const float4*)(qb + row * D + c4);
        qsT[c4 + 0][row] = x.x * SCALE;
        qsT[c4 + 1][row] = x.y * SCALE;
        qsT[c4 + 2][row] = x.z * SCALE;
        qsT[c4 + 3][row] = x.w * SCALE;
    }

    float mrun[4], lrun[4], accO[4][4];
#pragma unroll
    for (int i = 0; i < 4; i++) {
        mrun[i] = -1e30f; lrun[i] = 0.f;
#pragma unroll
        for (int j = 0; j < 4; j++) accO[i][j] = 0.f;
    }

    for (int kt = 0; kt < T / 64; kt++) {
        __syncthreads();   // prev-iter psT reads + (first iter) qsT writes done
        const float* kb = kb0 + (size_t)kt * 64 * D;
        const float* vb = vb0 + (size_t)kt * 64 * D;
#pragma unroll
        for (int it = 0; it < 4; it++) {
            int ff = tid + it * 256;
            int row = ff >> 4, c4 = (ff & 15) * 4;
            float4 x = *(const float4*)(kb + row * D + c4);
            kp[c4 + 0][row] = x.x;
            kp[c4 + 1][row] = x.y;
            kp[c4 + 2][row] = x.z;
            kp[c4 + 3][row] = x.w;
            float4 y = *(const float4*)(vb + row * D + c4);
            *(float4*)&vs[row][c4] = y;
        }
        __syncthreads();

        // S = q_scaled @ k^T  (outer product over d)
        float accS[4][4] = {};
#pragma unroll 8
        for (int d = 0; d < 64; d++) {
            float4 av = *(float4*)&qsT[d][ty * 4];
            float4 bv = *(float4*)&kp[d][tx * 4];
            float a[4] = {av.x, av.y, av.z, av.w};
            float b[4] = {bv.x, bv.y, bv.z, bv.w};
#pragma unroll
            for (int i = 0; i < 4; i++)
#pragma unroll
                for (int j = 0; j < 4; j++)
                    accS[i][j] = fmaf(a[i], b[j], accS[i][j]);
        }

        // online softmax; row r = ty*4+i spans the 16 tx-lanes (contiguous in wave)
        float alpha[4];
#pragma unroll
        for (int i = 0; i < 4; i++) {
            float mx = fmaxf(fmaxf(accS[i][0], accS[i][1]),
                             fmaxf(accS[i][2], accS[i][3]));
            mx = fmaxf(mx, __shfl_xor(mx, 1, 16));
            mx = fmaxf(mx, __shfl_xor(mx, 2, 16));
            mx = fmaxf(mx, __shfl_xor(mx, 4, 16));
            mx = fmaxf(mx, __shfl_xor(mx, 8, 16));
            float mnew = fmaxf(mrun[i], mx);
            alpha[i] = expf(mrun[i] - mnew);
            mrun[i] = mnew;
            float ps = 0.f;
#pragma unroll
            for (int j = 0; j < 4; j++) {
                float p = expf(accS[i][j] - mnew);
                accS[i][j] = p;
                ps += p;
            }
            ps += __shfl_xor(ps, 1, 16);
            ps += __shfl_xor(ps, 2, 16);
            ps += __shfl_xor(ps, 4, 16);
            ps += __shfl_xor(ps, 8, 16);
            lrun[i] = lrun[i] * alpha[i] + ps;
#pragma unroll
            for (int j = 0; j < 4; j++) accO[i][j] *= alpha[i];
        }

        __syncthreads();   // everyone done reading kp as k^T
        // write p^T [c][r] into kp
#pragma unroll
        for (int j = 0; j < 4; j++)
#pragma unroll
            for (int i = 0; i < 4; i++)
                kp[tx * 4 + j][ty * 4 + i] = accS[i][j];
        __syncthreads();

        // O += P @ V (outer product over c)
#pragma unroll 8
        for (int c = 0; c < 64; c++) {
            float4 pv = *(float4*)&kp[c][ty * 4];
            float4 vv = *(float4*)&vs[c][tx * 4];
            float a[4] = {pv.x, pv.y, pv.z, pv.w};
            float b[4] = {vv.x, vv.y, vv.z, vv.w};
#pragma unroll
            for (int i = 0; i < 4; i++)
#pragma unroll
                for (int j = 0; j < 4; j++)
                    accO[i][j] = fmaf(a[i], b[j], accO[i][j]);
        }
    }

    // epilogue: normalize and write (B, T, H*64)
    const int b_ = bh >> 4, h_ = bh & 15;
    float* ob = o + ((size_t)b_ * T + qt * 64) * C + h_ * 64;
#pragma unroll
    for (int i = 0; i < 4; i++) {
        float inv = 1.0f / lrun[i];
        float4 r;
        r.x = accO[i][0] * inv;
        r.y = accO[i][1] * inv;
        r.z = accO[i][2] * inv;
        r.w = accO[i][3] * inv;
        *(float4*)(ob + (size_t)(ty * 4 + i) * C + tx * 4) = r;
    }
}

// ---------------------------------------------------------------------------
extern "C" void kernel_launch(void* const* d_in, const int* in_sizes, int n_in,
                              void* d_out, int out_size, void* d_ws, size_t ws_size,
                              hipStream_t stream)
{
    const float* Q  = (const float*)d_in[0];
    const float* K  = (const float*)d_in[1];
    const float* V  = (const float*)d_in[2];
    const float* Wq = (const float*)d_in[3];
    const float* bq = (const float*)d_in[4];
    const float* Wk = (const float*)d_in[5];
    const float* bk = (const float*)d_in[6];
    const float* Wv = (const float*)d_in[7];
    const float* bv = (const float*)d_in[8];
    const float* Wo = (const float*)d_in[9];
    const float* bo = (const float*)d_in[10];
    float* out = (float*)d_out;

    // workspace: q, k, v in (B*H, T, 64); o in (B, T, 1024). 4 x 16 MB = 64 MB.
    float* qw = (float*)d_ws;
    float* kw = qw + (size_t)M * 1024;
    float* vw = kw + (size_t)M * 1024;
    float* ow = vw + (size_t)M * 1024;

    dim3 gg(1024 / 64, M / 64);   // (16, 64)
    dim3 blk(256);
    gemm_bias<<<gg, blk, 0, stream>>>(Q, Wq, bq, qw, 1);
    gemm_bias<<<gg, blk, 0, stream>>>(K, Wk, bk, kw, 1);
    gemm_bias<<<gg, blk, 0, stream>>>(V, Wv, bv, vw, 1);
    attn<<<dim3(T / 64, B * H), blk, 0, stream>>>(qw, kw, vw, ow);
    gemm_bias<<<gg, blk, 0, stream>>>(ow, Wo, bo, out, 0);
}

// Round 2
// 710.381 us; speedup vs baseline: 1.6859x; 1.6859x over previous
//
#include <hip/hip_runtime.h>
#include <hip/hip_bf16.h>
#include <math.h>

// Problem constants (hardcoded per reference)
constexpr int B = 2, T = 2048, C = 1024, H = 16, D = 64;
constexpr int M = B * T;          // 4096 rows for all projections
constexpr float SCALE = 0.125f;   // 1/sqrt(64)

typedef __attribute__((ext_vector_type(8))) short s16x8;  // 8 bf16 = 4 VGPRs
typedef __attribute__((ext_vector_type(4))) short s16x4;  // 4 bf16 = 8 B
typedef __attribute__((ext_vector_type(4))) float fv4;    // MFMA C/D

// ---------------------------------------------------------------------------
// GEMM: out = (A(M x 1024) @ W(1024 x 1024) + bias) * premul
// scatter=1: write bf16 to (B*H, T, 64) head-split layout (for attention)
// scatter=0: write fp32 row-major (M x 1024) (final output)
// Tile: BM=64, BN=64, BK=16; 256 threads; 4x4 per thread. fp32 math.
// ---------------------------------------------------------------------------
__global__ __launch_bounds__(256) void gemm_bias(
    const float* __restrict__ A, const float* __restrict__ W,
    const float* __restrict__ bias, float* __restrict__ outf,
    __hip_bfloat16* __restrict__ outh, int scatter, float premul)
{
    __shared__ float asT[16][68];   // [k][m], transposed A tile
    __shared__ float bs[16][68];    // [k][n]

    const int tid = threadIdx.x;
    const int ty = tid >> 4, tx = tid & 15;
    const int m0 = blockIdx.y * 64, n0 = blockIdx.x * 64;

    const int lm  = tid >> 2;          // 0..63  A row
    const int lk4 = (tid & 3) * 4;     // 0,4,8,12 k offset
    const int lkb = tid >> 4;          // 0..15  W row (k)
    const int ln4 = (tid & 15) * 4;    // 0..60  n offset

    const float* Ap = A + (size_t)(m0 + lm) * 1024 + lk4;
    const float* Wp = W + (size_t)lkb * 1024 + n0 + ln4;

    float acc[4][4] = {};

    for (int k0 = 0; k0 < 1024; k0 += 16) {
        float4 a4 = *(const float4*)(Ap + k0);
        float4 b4 = *(const float4*)(Wp + (size_t)k0 * 1024);
        __syncthreads();
        asT[lk4 + 0][lm] = a4.x;
        asT[lk4 + 1][lm] = a4.y;
        asT[lk4 + 2][lm] = a4.z;
        asT[lk4 + 3][lm] = a4.w;
        *(float4*)&bs[lkb][ln4] = b4;
        __syncthreads();
#pragma unroll
        for (int kk = 0; kk < 16; kk++) {
            float4 av = *(float4*)&asT[kk][ty * 4];
            float4 bv = *(float4*)&bs[kk][tx * 4];
            float a[4] = {av.x, av.y, av.z, av.w};
            float b[4] = {bv.x, bv.y, bv.z, bv.w};
#pragma unroll
            for (int i = 0; i < 4; i++)
#pragma unroll
                for (int j = 0; j < 4; j++)
                    acc[i][j] = fmaf(a[i], b[j], acc[i][j]);
        }
    }

    float4 bb = *(const float4*)(bias + n0 + tx * 4);
    const float badd[4] = {bb.x, bb.y, bb.z, bb.w};

#pragma unroll
    for (int i = 0; i < 4; i++) {
        float rr[4];
#pragma unroll
        for (int j = 0; j < 4; j++) rr[j] = (acc[i][j] + badd[j]) * premul;
        const int m_ = m0 + ty * 4 + i;
        if (scatter) {
            const int b_ = m_ >> 11;           // /T
            const int t_ = m_ & (T - 1);
            const int h_ = n0 >> 6;            // n0 is 64-aligned
            const int d_ = tx * 4;
            union { s16x4 s; __hip_bfloat16 h[4]; } u;
#pragma unroll
            for (int j = 0; j < 4; j++) u.h[j] = __float2bfloat16(rr[j]);
            *(s16x4*)(outh + (((size_t)(b_ * H + h_) * T + t_) * D) + d_) = u.s;
        } else {
            float4 r = {rr[0], rr[1], rr[2], rr[3]};
            *(float4*)(outf + (size_t)m_ * 1024 + n0 + tx * 4) = r;
        }
    }
}

// ---------------------------------------------------------------------------
// Transpose V: (B*H, T, 64) bf16 -> (B*H, 64, T) bf16, 64x64 tiles via LDS.
// ---------------------------------------------------------------------------
__global__ __launch_bounds__(256) void transpose_v(
    const __hip_bfloat16* __restrict__ vw, __hip_bfloat16* __restrict__ vt)
{
    __shared__ __hip_bfloat16 tile[64][74];   // pad 74 -> 2-way max on gather
    const int tid = threadIdx.x;
    const int t0 = blockIdx.x * 64;
    const int bh = blockIdx.y;

    const __hip_bfloat16* src = vw + ((size_t)bh * T + t0) * D;
#pragma unroll
    for (int it = 0; it < 2; it++) {
        int f = it * 256 + tid;
        int row = f >> 3, c8 = (f & 7) * 8;
        *(s16x8*)&tile[row][c8] = *(const s16x8*)(src + (size_t)row * D + c8);
    }
    __syncthreads();
    __hip_bfloat16* dst = vt + (size_t)bh * D * T + t0;
#pragma unroll
    for (int it = 0; it < 4; it++) {
        int f = it * 256 + tid;
        int d = f >> 4, t4 = (f & 15) * 4;
        union { s16x4 s; __hip_bfloat16 h[4]; } u;
#pragma unroll
        for (int j = 0; j < 4; j++) u.h[j] = tile[t4 + j][d];
        *(s16x4*)(dst + (size_t)d * T + t4) = u.s;
    }
}

// ---------------------------------------------------------------------------
// Flash attention, bf16 MFMA 16x16x32.
// q,k: (B*H, T, 64) bf16 (q pre-scaled). vT: (B*H, 64, T) bf16.
// o: (B, T, 1024) fp32.
// Block: 256 threads = 4 waves; 64 q-rows per block (16 per wave); K-tile 64.
// Layouts (measured m89/m120): A[m=lane&15][k=quad*8+j],
//   B[k=quad*8+j][n=lane&15], C/D[row=quad*4+r][col=lane&15].
// ---------------------------------------------------------------------------
__global__ __launch_bounds__(256) void attn(
    const __hip_bfloat16* __restrict__ q, const __hip_bfloat16* __restrict__ k,
    const __hip_bfloat16* __restrict__ vT, float* __restrict__ o)
{
    __shared__ __hip_bfloat16 qs[64][72];    // [qrow][d]     (stride 144B)
    __shared__ __hip_bfloat16 ks[64][72];    // [key][d]
    __shared__ __hip_bfloat16 vsT[64][72];   // [vdim][key]
    __shared__ __hip_bfloat16 ps[64][72];    // [qrow][key]   wave-private strips

    const int tid = threadIdx.x;
    const int w = tid >> 6;        // wave 0..3
    const int lane = tid & 63;
    const int quad = lane >> 4;    // 0..3
    const int lc = lane & 15;
    const int qt = blockIdx.x;     // 0..31 query tile
    const int bh = blockIdx.y;     // 0..31

    // stage q tile (already scaled by 1/sqrt(dk) in projection epilogue)
    const __hip_bfloat16* qb = q + ((size_t)bh * T + qt * 64) * D;
#pragma unroll
    for (int it = 0; it < 2; it++) {
        int f = it * 256 + tid;
        int row = f >> 3, c8 = (f & 7) * 8;
        *(s16x8*)&qs[row][c8] = *(const s16x8*)(qb + (size_t)row * D + c8);
    }
    __syncthreads();

    // A-fragments of Q are loop-invariant: hoist
    const s16x8 aq0 = *(const s16x8*)&qs[16 * w + lc][8 * quad];
    const s16x8 aq1 = *(const s16x8*)&qs[16 * w + lc][32 + 8 * quad];

    fv4 accO[4] = {};               // accO[t][r] = O[4*quad+r][t*16+lc]
    float mrun[4], lrun[4];
#pragma unroll
    for (int r = 0; r < 4; r++) { mrun[r] = -1e30f; lrun[r] = 0.f; }

    const __hip_bfloat16* kb0 = k + (size_t)bh * T * D;
    const __hip_bfloat16* vb0 = vT + (size_t)bh * D * T;

    for (int kt = 0; kt < T / 64; kt++) {
        __syncthreads();   // protect prev iteration's ks/vsT reads
#pragma unroll
        for (int it = 0; it < 2; it++) {
            int f = it * 256 + tid;
            int row = f >> 3, c8 = (f & 7) * 8;
            *(s16x8*)&ks[row][c8] =
                *(const s16x8*)(kb0 + (size_t)(kt * 64 + row) * D + c8);
            *(s16x8*)&vsT[row][c8] =
                *(const s16x8*)(vb0 + (size_t)row * T + kt * 64 + c8);
        }
        __syncthreads();

        // S = q @ k^T  (already scaled)
        fv4 accS[4] = {};
#pragma unroll
        for (int t = 0; t < 4; t++) {
            s16x8 b0 = *(const s16x8*)&ks[t * 16 + lc][8 * quad];
            s16x8 b1 = *(const s16x8*)&ks[t * 16 + lc][32 + 8 * quad];
            accS[t] = __builtin_amdgcn_mfma_f32_16x16x32_bf16(aq0, b0, accS[t], 0, 0, 0);
            accS[t] = __builtin_amdgcn_mfma_f32_16x16x32_bf16(aq1, b1, accS[t], 0, 0, 0);
        }

        // online softmax; rows 4*quad+r live across the 16 lanes of this quad
#pragma unroll
        for (int r = 0; r < 4; r++) {
            float mx = fmaxf(fmaxf(accS[0][r], accS[1][r]),
                             fmaxf(accS[2][r], accS[3][r]));
            mx = fmaxf(mx, __shfl_xor(mx, 1));
            mx = fmaxf(mx, __shfl_xor(mx, 2));
            mx = fmaxf(mx, __shfl_xor(mx, 4));
            mx = fmaxf(mx, __shfl_xor(mx, 8));
            float mnew = fmaxf(mrun[r], mx);
            float alpha = __expf(mrun[r] - mnew);
            float psum = 0.f;
#pragma unroll
            for (int t = 0; t < 4; t++) {
                float p = __expf(accS[t][r] - mnew);
                ps[16 * w + 4 * quad + r][t * 16 + lc] = __float2bfloat16(p);
                psum += p;
            }
            psum += __shfl_xor(psum, 1);
            psum += __shfl_xor(psum, 2);
            psum += __shfl_xor(psum, 4);
            psum += __shfl_xor(psum, 8);
            lrun[r] = lrun[r] * alpha + psum;
            mrun[r] = mnew;
#pragma unroll
            for (int t = 0; t < 4; t++) accO[t][r] *= alpha;
        }

        // O += P @ V. ps strip is wave-private: same-wave DS ordering (lgkmcnt)
        // makes the write->read safe with no barrier.
        s16x8 pa0 = *(const s16x8*)&ps[16 * w + lc][8 * quad];
        s16x8 pa1 = *(const s16x8*)&ps[16 * w + lc][32 + 8 * quad];
#pragma unroll
        for (int t = 0; t < 4; t++) {
            s16x8 b0 = *(const s16x8*)&vsT[t * 16 + lc][8 * quad];
            s16x8 b1 = *(const s16x8*)&vsT[t * 16 + lc][32 + 8 * quad];
            accO[t] = __builtin_amdgcn_mfma_f32_16x16x32_bf16(pa0, b0, accO[t], 0, 0, 0);
            accO[t] = __builtin_amdgcn_mfma_f32_16x16x32_bf16(pa1, b1, accO[t], 0, 0, 0);
        }
    }

    // epilogue: normalize, write (B, T, H*64) fp32
    const int b_ = bh >> 4, h_ = bh & 15;
#pragma unroll
    for (int r = 0; r < 4; r++) {
        float inv = 1.0f / lrun[r];
        int row = qt * 64 + 16 * w + 4 * quad + r;
        float* op = o + ((size_t)b_ * T + row) * C + h_ * 64;
#pragma unroll
        for (int t = 0; t < 4; t++)
            op[t * 16 + lc] = accO[t][r] * inv;
    }
}

// ---------------------------------------------------------------------------
extern "C" void kernel_launch(void* const* d_in, const int* in_sizes, int n_in,
                              void* d_out, int out_size, void* d_ws, size_t ws_size,
                              hipStream_t stream)
{
    const float* Q  = (const float*)d_in[0];
    const float* K  = (const float*)d_in[1];
    const float* V  = (const float*)d_in[2];
    const float* Wq = (const float*)d_in[3];
    const float* bq = (const float*)d_in[4];
    const float* Wk = (const float*)d_in[5];
    const float* bk = (const float*)d_in[6];
    const float* Wv = (const float*)d_in[7];
    const float* bv = (const float*)d_in[8];
    const float* Wo = (const float*)d_in[9];
    const float* bo = (const float*)d_in[10];
    float* out = (float*)d_out;

    // ws: q,k,v,vT bf16 (8 MB each) + o fp32 (16 MB) = 48 MB
    __hip_bfloat16* qw = (__hip_bfloat16*)d_ws;
    __hip_bfloat16* kw = qw + (size_t)M * 1024;
    __hip_bfloat16* vw = kw + (size_t)M * 1024;
    __hip_bfloat16* vt = vw + (size_t)M * 1024;
    float* ow = (float*)(vt + (size_t)M * 1024);

    dim3 gg(16, 64), blk(256);
    gemm_bias<<<gg, blk, 0, stream>>>(Q, Wq, bq, nullptr, qw, 1, SCALE);
    gemm_bias<<<gg, blk, 0, stream>>>(K, Wk, bk, nullptr, kw, 1, 1.0f);
    gemm_bias<<<gg, blk, 0, stream>>>(V, Wv, bv, nullptr, vw, 1, 1.0f);
    transpose_v<<<dim3(T / 64, B * H), blk, 0, stream>>>(vw, vt);
    attn<<<dim3(T / 64, B * H), blk, 0, stream>>>(qw, kw, vt, ow);
    gemm_bias<<<gg, blk, 0, stream>>>(ow, Wo, bo, out, nullptr, 0, 1.0f);
}

// Round 4
// 303.886 us; speedup vs baseline: 3.9411x; 2.3377x over previous
//
#include <hip/hip_runtime.h>
#include <hip/hip_bf16.h>
#include <math.h>

constexpr int B = 2, T = 2048, C = 1024, H = 16, D = 64;
constexpr int M = B * T;          // 4096
constexpr float SCALE = 0.125f;   // 1/sqrt(64)

typedef __attribute__((ext_vector_type(8))) short s16x8;  // 8 bf16 = 4 VGPRs
typedef __attribute__((ext_vector_type(4))) short s16x4;
typedef __attribute__((ext_vector_type(4))) float fv4;

typedef unsigned short ushort_t;

static __device__ __forceinline__ ushort_t f2bf(float x) {
    union { __hip_bfloat16 h; ushort_t u; } c;
    c.h = __float2bfloat16(x);
    return c.u;
}

// global->LDS async copy, 16B per lane. LDS dest is WAVE-UNIFORM base +
// lane*16B (m104/m108) — pass a wave-uniform lp!
#define GLDS(gp, lp) __builtin_amdgcn_global_load_lds( \
    (const __attribute__((address_space(1))) void*)(gp), \
    (__attribute__((address_space(3))) void*)(lp), 16, 0, 0)

// ---------------------------------------------------------------------------
// fp32 -> bf16 convert for Q,K,V (concatenated dst: 3 x 4M elements)
// ---------------------------------------------------------------------------
__global__ __launch_bounds__(256) void convert_qkv(
    const float* __restrict__ Q, const float* __restrict__ K,
    const float* __restrict__ V, ushort_t* __restrict__ dst)
{
    size_t e = ((size_t)blockIdx.x * 256 + threadIdx.x) * 8;
    const float* src;
    size_t base;
    if (e < (size_t)M * C)          { src = Q; base = 0; }
    else if (e < 2 * (size_t)M * C) { src = K; base = (size_t)M * C; }
    else                            { src = V; base = 2 * (size_t)M * C; }
    const float* p = src + (e - base);
    float4 a = *(const float4*)p;
    float4 b = *(const float4*)(p + 4);
    union { s16x8 v; ushort_t u[8]; } o;
    o.u[0] = f2bf(a.x); o.u[1] = f2bf(a.y); o.u[2] = f2bf(a.z); o.u[3] = f2bf(a.w);
    o.u[4] = f2bf(b.x); o.u[5] = f2bf(b.y); o.u[6] = f2bf(b.z); o.u[7] = f2bf(b.w);
    *(s16x8*)(dst + e) = o.v;
}

// ---------------------------------------------------------------------------
// Transpose + convert weights: Wt[s*1024 + n][k] = Ws[k][n], bf16.
// s = 0..3 -> Wq, Wk, Wv, Wo. 64x64 tiles.
// ---------------------------------------------------------------------------
__global__ __launch_bounds__(256) void transpose_w(
    const float* __restrict__ W0, const float* __restrict__ W1,
    const float* __restrict__ W2, const float* __restrict__ W3,
    ushort_t* __restrict__ Wt)
{
    const int s = blockIdx.z;
    const float* W = (s == 0) ? W0 : (s == 1) ? W1 : (s == 2) ? W2 : W3;
    const int k0 = blockIdx.x * 64, n0 = blockIdx.y * 64;
    __shared__ ushort_t tile[64][72];
    const int tid = threadIdx.x;
#pragma unroll
    for (int it = 0; it < 4; it++) {
        int f = it * 256 + tid;
        int r = f >> 4, c4 = (f & 15) * 4;
        float4 x = *(const float4*)(W + (size_t)(k0 + r) * C + n0 + c4);
        tile[r][c4 + 0] = f2bf(x.x);
        tile[r][c4 + 1] = f2bf(x.y);
        tile[r][c4 + 2] = f2bf(x.z);
        tile[r][c4 + 3] = f2bf(x.w);
    }
    __syncthreads();
#pragma unroll
    for (int it = 0; it < 4; it++) {
        int f = it * 256 + tid;
        int rr = f >> 4, c4 = (f & 15) * 4;   // rr: n-local, c4: k-local
        union { s16x4 v; ushort_t u[4]; } u;
#pragma unroll
        for (int j = 0; j < 4; j++) u.u[j] = tile[c4 + j][rr];
        *(s16x4*)(Wt + (size_t)(s * 1024 + n0 + rr) * 1024 + k0 + c4) = u.v;
    }
}

// ---------------------------------------------------------------------------
// Fused QKV projection GEMM, bf16 MFMA (m97 structure).
// C = A @ Wt^T + bias, scaled; scatter per section:
//   s=0,1 -> (BH, T, 64);  s=2 -> (BH, 64, T)  (direct V^T)
// Tile 128x128, BK=32, 256 threads (4 waves, 2x2), 16 MFMA/iter/wave.
// LDS stage layout: As[row][32], row-major; per (iter i, wave w) GLDS base
// = element (i*64 + w*16)*32 = i*2048 + w*512 (wave-uniform).
// ---------------------------------------------------------------------------
__global__ __launch_bounds__(256) void gemm_qkv(
    const ushort_t* __restrict__ qkv, const ushort_t* __restrict__ Wt,
    const float* __restrict__ bq, const float* __restrict__ bk,
    const float* __restrict__ bv,
    ushort_t* __restrict__ qw, ushort_t* __restrict__ kw,
    ushort_t* __restrict__ vt)
{
    __shared__ ushort_t As[128 * 32];
    __shared__ ushort_t Bs[128 * 32];

    const int tid = threadIdx.x;
    const int w = tid >> 6, lane = tid & 63;
    const int quad = lane >> 4, lc = lane & 15;
    const int wm = w & 1, wn = w >> 1;

    const int nt = blockIdx.x;          // 0..23
    const int m0 = blockIdx.y * 128;
    const int s = nt >> 3;              // section 0,1,2
    const int nsec0 = (nt & 7) * 128;   // n within section

    const ushort_t* Abase = qkv + (size_t)s * M * C;
    const ushort_t* Btbase = Wt + (size_t)nt * 128 * 1024;

    const int srow = (w << 4) + (lane >> 2);   // 0..63 staging row
    const int ske  = (lane & 3) * 8;           // k elem offset within 32

    fv4 acc[4][4] = {};

    for (int k0 = 0; k0 < 1024; k0 += 32) {
        __syncthreads();
#pragma unroll
        for (int i = 0; i < 2; i++) {
            int row = i * 64 + srow;
            GLDS(Abase + (size_t)(m0 + row) * 1024 + k0 + ske,
                 As + i * 2048 + w * 512);
            GLDS(Btbase + (size_t)row * 1024 + k0 + ske,
                 Bs + i * 2048 + w * 512);
        }
        __syncthreads();

        s16x8 af[4], bf[4];
#pragma unroll
        for (int ms = 0; ms < 4; ms++)
            af[ms] = *(const s16x8*)(As + (wm * 64 + ms * 16 + lc) * 32 + quad * 8);
#pragma unroll
        for (int ns = 0; ns < 4; ns++)
            bf[ns] = *(const s16x8*)(Bs + (wn * 64 + ns * 16 + lc) * 32 + quad * 8);
#pragma unroll
        for (int ms = 0; ms < 4; ms++)
#pragma unroll
            for (int ns = 0; ns < 4; ns++)
                acc[ms][ns] = __builtin_amdgcn_mfma_f32_16x16x32_bf16(
                    af[ms], bf[ns], acc[ms][ns], 0, 0, 0);
    }

    const float* biasp = (s == 0) ? bq : (s == 1) ? bk : bv;
    const float premul = (s == 0) ? SCALE : 1.0f;
    ushort_t* outp = (s == 0) ? qw : (s == 1) ? kw : vt;

#pragma unroll
    for (int ns = 0; ns < 4; ns++) {
        const int nl = nsec0 + wn * 64 + ns * 16 + lc;   // n within [0,1024)
        const float bias = biasp[nl];
        const int h_ = nl >> 6, d_ = nl & 63;
#pragma unroll
        for (int ms = 0; ms < 4; ms++) {
#pragma unroll
            for (int r = 0; r < 4; r++) {
                int m = m0 + wm * 64 + ms * 16 + quad * 4 + r;
                float val = (acc[ms][ns][r] + bias) * premul;
                ushort_t hv = f2bf(val);
                int b_ = m >> 11, t_ = m & (T - 1);
                size_t bh = (size_t)(b_ * H + h_);
                if (s < 2)
                    outp[((bh * T + t_) << 6) + d_] = hv;        // (BH,T,64)
                else
                    outp[(bh * 64 + d_) * T + t_] = hv;          // (BH,64,T)
            }
        }
    }
}

// ---------------------------------------------------------------------------
// Final projection: out = o(4096x1024)bf16 @ Wot^T + bo, fp32 out.
// ---------------------------------------------------------------------------
__global__ __launch_bounds__(256) void gemm_final(
    const ushort_t* __restrict__ A, const ushort_t* __restrict__ Wot,
    const float* __restrict__ bo, float* __restrict__ out)
{
    __shared__ ushort_t As[128 * 32];
    __shared__ ushort_t Bs[128 * 32];

    const int tid = threadIdx.x;
    const int w = tid >> 6, lane = tid & 63;
    const int quad = lane >> 4, lc = lane & 15;
    const int wm = w & 1, wn = w >> 1;

    const int n0 = blockIdx.x * 128;
    const int m0 = blockIdx.y * 128;

    const int srow = (w << 4) + (lane >> 2);
    const int ske  = (lane & 3) * 8;

    fv4 acc[4][4] = {};

    for (int k0 = 0; k0 < 1024; k0 += 32) {
        __syncthreads();
#pragma unroll
        for (int i = 0; i < 2; i++) {
            int row = i * 64 + srow;
            GLDS(A + (size_t)(m0 + row) * 1024 + k0 + ske,
                 As + i * 2048 + w * 512);
            GLDS(Wot + (size_t)(n0 + row) * 1024 + k0 + ske,
                 Bs + i * 2048 + w * 512);
        }
        __syncthreads();

        s16x8 af[4], bf[4];
#pragma unroll
        for (int ms = 0; ms < 4; ms++)
            af[ms] = *(const s16x8*)(As + (wm * 64 + ms * 16 + lc) * 32 + quad * 8);
#pragma unroll
        for (int ns = 0; ns < 4; ns++)
            bf[ns] = *(const s16x8*)(Bs + (wn * 64 + ns * 16 + lc) * 32 + quad * 8);
#pragma unroll
        for (int ms = 0; ms < 4; ms++)
#pragma unroll
            for (int ns = 0; ns < 4; ns++)
                acc[ms][ns] = __builtin_amdgcn_mfma_f32_16x16x32_bf16(
                    af[ms], bf[ns], acc[ms][ns], 0, 0, 0);
    }

#pragma unroll
    for (int ns = 0; ns < 4; ns++) {
        const int n = n0 + wn * 64 + ns * 16 + lc;
        const float bias = bo[n];
#pragma unroll
        for (int ms = 0; ms < 4; ms++) {
#pragma unroll
            for (int r = 0; r < 4; r++) {
                int m = m0 + wm * 64 + ms * 16 + quad * 4 + r;
                out[(size_t)m * 1024 + n] = acc[ms][ns][r] + bias;
            }
        }
    }
}

// ---------------------------------------------------------------------------
// Flash attention, bf16 MFMA 16x16x32 (unchanged from R2 except bf16 o).
// ---------------------------------------------------------------------------
__global__ __launch_bounds__(256) void attn(
    const ushort_t* __restrict__ q, const ushort_t* __restrict__ k,
    const ushort_t* __restrict__ vT, ushort_t* __restrict__ o)
{
    __shared__ ushort_t qs[64][72];
    __shared__ ushort_t ks[64][72];
    __shared__ ushort_t vsT[64][72];
    __shared__ ushort_t ps[64][72];

    const int tid = threadIdx.x;
    const int w = tid >> 6;
    const int lane = tid & 63;
    const int quad = lane >> 4;
    const int lc = lane & 15;
    const int qt = blockIdx.x;
    const int bh = blockIdx.y;

    const ushort_t* qb = q + ((size_t)bh * T + qt * 64) * D;
#pragma unroll
    for (int it = 0; it < 2; it++) {
        int f = it * 256 + tid;
        int row = f >> 3, c8 = (f & 7) * 8;
        *(s16x8*)&qs[row][c8] = *(const s16x8*)(qb + (size_t)row * D + c8);
    }
    __syncthreads();

    const s16x8 aq0 = *(const s16x8*)&qs[16 * w + lc][8 * quad];
    const s16x8 aq1 = *(const s16x8*)&qs[16 * w + lc][32 + 8 * quad];

    fv4 accO[4] = {};
    float mrun[4], lrun[4];
#pragma unroll
    for (int r = 0; r < 4; r++) { mrun[r] = -1e30f; lrun[r] = 0.f; }

    const ushort_t* kb0 = k + (size_t)bh * T * D;
    const ushort_t* vb0 = vT + (size_t)bh * D * T;

    for (int kt = 0; kt < T / 64; kt++) {
        __syncthreads();
#pragma unroll
        for (int it = 0; it < 2; it++) {
            int f = it * 256 + tid;
            int row = f >> 3, c8 = (f & 7) * 8;
            *(s16x8*)&ks[row][c8] =
                *(const s16x8*)(kb0 + (size_t)(kt * 64 + row) * D + c8);
            *(s16x8*)&vsT[row][c8] =
                *(const s16x8*)(vb0 + (size_t)row * T + kt * 64 + c8);
        }
        __syncthreads();

        fv4 accS[4] = {};
#pragma unroll
        for (int t = 0; t < 4; t++) {
            s16x8 b0 = *(const s16x8*)&ks[t * 16 + lc][8 * quad];
            s16x8 b1 = *(const s16x8*)&ks[t * 16 + lc][32 + 8 * quad];
            accS[t] = __builtin_amdgcn_mfma_f32_16x16x32_bf16(aq0, b0, accS[t], 0, 0, 0);
            accS[t] = __builtin_amdgcn_mfma_f32_16x16x32_bf16(aq1, b1, accS[t], 0, 0, 0);
        }

#pragma unroll
        for (int r = 0; r < 4; r++) {
            float mx = fmaxf(fmaxf(accS[0][r], accS[1][r]),
                             fmaxf(accS[2][r], accS[3][r]));
            mx = fmaxf(mx, __shfl_xor(mx, 1));
            mx = fmaxf(mx, __shfl_xor(mx, 2));
            mx = fmaxf(mx, __shfl_xor(mx, 4));
            mx = fmaxf(mx, __shfl_xor(mx, 8));
            float mnew = fmaxf(mrun[r], mx);
            float alpha = __expf(mrun[r] - mnew);
            float psum = 0.f;
#pragma unroll
            for (int t = 0; t < 4; t++) {
                float p = __expf(accS[t][r] - mnew);
                ps[16 * w + 4 * quad + r][t * 16 + lc] = f2bf(p);
                psum += p;
            }
            psum += __shfl_xor(psum, 1);
            psum += __shfl_xor(psum, 2);
            psum += __shfl_xor(psum, 4);
            psum += __shfl_xor(psum, 8);
            lrun[r] = lrun[r] * alpha + psum;
            mrun[r] = mnew;
#pragma unroll
            for (int t = 0; t < 4; t++) accO[t][r] *= alpha;
        }

        s16x8 pa0 = *(const s16x8*)&ps[16 * w + lc][8 * quad];
        s16x8 pa1 = *(const s16x8*)&ps[16 * w + lc][32 + 8 * quad];
#pragma unroll
        for (int t = 0; t < 4; t++) {
            s16x8 b0 = *(const s16x8*)&vsT[t * 16 + lc][8 * quad];
            s16x8 b1 = *(const s16x8*)&vsT[t * 16 + lc][32 + 8 * quad];
            accO[t] = __builtin_amdgcn_mfma_f32_16x16x32_bf16(pa0, b0, accO[t], 0, 0, 0);
            accO[t] = __builtin_amdgcn_mfma_f32_16x16x32_bf16(pa1, b1, accO[t], 0, 0, 0);
        }
    }

    const int b_ = bh >> 4, h_ = bh & 15;
#pragma unroll
    for (int r = 0; r < 4; r++) {
        float inv = 1.0f / lrun[r];
        int row = qt * 64 + 16 * w + 4 * quad + r;
        ushort_t* op = o + ((size_t)b_ * T + row) * C + h_ * 64;
#pragma unroll
        for (int t = 0; t < 4; t++)
            op[t * 16 + lc] = f2bf(accO[t][r] * inv);
    }
}

// ---------------------------------------------------------------------------
extern "C" void kernel_launch(void* const* d_in, const int* in_sizes, int n_in,
                              void* d_out, int out_size, void* d_ws, size_t ws_size,
                              hipStream_t stream)
{
    const float* Q  = (const float*)d_in[0];
    const float* K  = (const float*)d_in[1];
    const float* V  = (const float*)d_in[2];
    const float* Wq = (const float*)d_in[3];
    const float* bq = (const float*)d_in[4];
    const float* Wk = (const float*)d_in[5];
    const float* bk = (const float*)d_in[6];
    const float* Wv = (const float*)d_in[7];
    const float* bv = (const float*)d_in[8];
    const float* Wo = (const float*)d_in[9];
    const float* bo = (const float*)d_in[10];
    float* out = (float*)d_out;

    // ws: qkvbf 24MB | Wt 8MB | qw 8MB | kw 8MB | vt 8MB | ow 8MB = 64MB
    ushort_t* qkvbf = (ushort_t*)d_ws;
    ushort_t* Wt = qkvbf + (size_t)3 * M * C;
    ushort_t* qw = Wt + (size_t)4096 * 1024;
    ushort_t* kw = qw + (size_t)M * C;
    ushort_t* vt = kw + (size_t)M * C;
    ushort_t* ow = vt + (size_t)M * C;
    ushort_t* Wot = Wt + (size_t)3072 * 1024;

    dim3 blk(256);
    convert_qkv<<<dim3(3 * M * C / 2048), blk, 0, stream>>>(Q, K, V, qkvbf);
    transpose_w<<<dim3(16, 16, 4), blk, 0, stream>>>(Wq, Wk, Wv, Wo, Wt);
    gemm_qkv<<<dim3(24, 32), blk, 0, stream>>>(qkvbf, Wt, bq, bk, bv, qw, kw, vt);
    attn<<<dim3(T / 64, B * H), blk, 0, stream>>>(qw, kw, vt, ow);
    gemm_final<<<dim3(8, 32), blk, 0, stream>>>(ow, Wot, bo, out);
}

// Round 5
// 260.857 us; speedup vs baseline: 4.5912x; 1.1650x over previous
//
#include <hip/hip_runtime.h>
#include <hip/hip_bf16.h>
#include <math.h>

constexpr int B = 2, T = 2048, C = 1024, H = 16, D = 64;
constexpr int M = B * T;          // 4096
constexpr float SCALE = 0.125f;   // 1/sqrt(64)

typedef __attribute__((ext_vector_type(8))) short s16x8;  // 8 bf16 = 4 VGPRs
typedef __attribute__((ext_vector_type(4))) short s16x4;
typedef __attribute__((ext_vector_type(4))) float fv4;

typedef unsigned short ushort_t;

static __device__ __forceinline__ ushort_t f2bf(float x) {
    union { __hip_bfloat16 h; ushort_t u; } c;
    c.h = __float2bfloat16(x);
    return c.u;
}

// global->LDS async copy, 16B per lane. LDS dest is WAVE-UNIFORM base +
// lane*16B (m104/m108) — pass a wave-uniform lp!
#define GLDS(gp, lp) __builtin_amdgcn_global_load_lds( \
    (const __attribute__((address_space(1))) void*)(gp), \
    (__attribute__((address_space(3))) void*)(lp), 16, 0, 0)

// ---------------------------------------------------------------------------
// fp32 -> bf16 convert for Q,K,V (concatenated dst: 3 x 4M elements)
// ---------------------------------------------------------------------------
__global__ __launch_bounds__(256) void convert_qkv(
    const float* __restrict__ Q, const float* __restrict__ K,
    const float* __restrict__ V, ushort_t* __restrict__ dst)
{
    size_t e = ((size_t)blockIdx.x * 256 + threadIdx.x) * 8;
    const float* src;
    size_t base;
    if (e < (size_t)M * C)          { src = Q; base = 0; }
    else if (e < 2 * (size_t)M * C) { src = K; base = (size_t)M * C; }
    else                            { src = V; base = 2 * (size_t)M * C; }
    const float* p = src + (e - base);
    float4 a = *(const float4*)p;
    float4 b = *(const float4*)(p + 4);
    union { s16x8 v; ushort_t u[8]; } o;
    o.u[0] = f2bf(a.x); o.u[1] = f2bf(a.y); o.u[2] = f2bf(a.z); o.u[3] = f2bf(a.w);
    o.u[4] = f2bf(b.x); o.u[5] = f2bf(b.y); o.u[6] = f2bf(b.z); o.u[7] = f2bf(b.w);
    *(s16x8*)(dst + e) = o.v;
}

// ---------------------------------------------------------------------------
// Transpose + convert weights: Wt[s*1024 + n][k] = Ws[k][n], bf16.
// ---------------------------------------------------------------------------
__global__ __launch_bounds__(256) void transpose_w(
    const float* __restrict__ W0, const float* __restrict__ W1,
    const float* __restrict__ W2, const float* __restrict__ W3,
    ushort_t* __restrict__ Wt)
{
    const int s = blockIdx.z;
    const float* W = (s == 0) ? W0 : (s == 1) ? W1 : (s == 2) ? W2 : W3;
    const int k0 = blockIdx.x * 64, n0 = blockIdx.y * 64;
    __shared__ ushort_t tile[64][72];
    const int tid = threadIdx.x;
#pragma unroll
    for (int it = 0; it < 4; it++) {
        int f = it * 256 + tid;
        int r = f >> 4, c4 = (f & 15) * 4;
        float4 x = *(const float4*)(W + (size_t)(k0 + r) * C + n0 + c4);
        tile[r][c4 + 0] = f2bf(x.x);
        tile[r][c4 + 1] = f2bf(x.y);
        tile[r][c4 + 2] = f2bf(x.z);
        tile[r][c4 + 3] = f2bf(x.w);
    }
    __syncthreads();
#pragma unroll
    for (int it = 0; it < 4; it++) {
        int f = it * 256 + tid;
        int rr = f >> 4, c4 = (f & 15) * 4;
        union { s16x4 v; ushort_t u[4]; } u;
#pragma unroll
        for (int j = 0; j < 4; j++) u.u[j] = tile[c4 + j][rr];
        *(s16x4*)(Wt + (size_t)(s * 1024 + n0 + rr) * 1024 + k0 + c4) = u.v;
    }
}

// ---------------------------------------------------------------------------
// Transpose V: (B*H, T, 64) bf16 -> (B*H, 64, T) bf16 (coalesced both sides).
// ---------------------------------------------------------------------------
__global__ __launch_bounds__(256) void transpose_v(
    const ushort_t* __restrict__ vw, ushort_t* __restrict__ vt)
{
    __shared__ ushort_t tile[64][72];
    const int tid = threadIdx.x;
    const int t0 = blockIdx.x * 64;
    const int bh = blockIdx.y;
    const ushort_t* src = vw + ((size_t)bh * T + t0) * D;
#pragma unroll
    for (int it = 0; it < 2; it++) {
        int f = it * 256 + tid;
        int row = f >> 3, c8 = (f & 7) * 8;
        *(s16x8*)&tile[row][c8] = *(const s16x8*)(src + (size_t)row * D + c8);
    }
    __syncthreads();
    ushort_t* dst = vt + (size_t)bh * D * T + t0;
#pragma unroll
    for (int it = 0; it < 4; it++) {
        int f = it * 256 + tid;
        int d = f >> 4, t4 = (f & 15) * 4;
        union { s16x4 v; ushort_t u[4]; } u;
#pragma unroll
        for (int j = 0; j < 4; j++) u.u[j] = tile[t4 + j][d];
        *(s16x4*)(dst + (size_t)d * T + t4) = u.v;
    }
}

// ---------------------------------------------------------------------------
// Fused QKV projection GEMM, bf16 MFMA (m97 structure).
// All sections now store coalesced (BH, T, 64); V transposed separately.
// ---------------------------------------------------------------------------
__global__ __launch_bounds__(256) void gemm_qkv(
    const ushort_t* __restrict__ qkv, const ushort_t* __restrict__ Wt,
    const float* __restrict__ bq, const float* __restrict__ bk,
    const float* __restrict__ bv,
    ushort_t* __restrict__ qw, ushort_t* __restrict__ kw,
    ushort_t* __restrict__ vw)
{
    __shared__ ushort_t As[128 * 32];
    __shared__ ushort_t Bs[128 * 32];

    const int tid = threadIdx.x;
    const int w = tid >> 6, lane = tid & 63;
    const int quad = lane >> 4, lc = lane & 15;
    const int wm = w & 1, wn = w >> 1;

    const int nt = blockIdx.x;          // 0..23
    const int m0 = blockIdx.y * 128;
    const int s = nt >> 3;              // 0,1,2
    const int nsec0 = (nt & 7) * 128;

    const ushort_t* Abase = qkv + (size_t)s * M * C;
    const ushort_t* Btbase = Wt + (size_t)nt * 128 * 1024;

    const int srow = (w << 4) + (lane >> 2);
    const int ske  = (lane & 3) * 8;

    fv4 acc[4][4] = {};

    for (int k0 = 0; k0 < 1024; k0 += 32) {
        __syncthreads();
#pragma unroll
        for (int i = 0; i < 2; i++) {
            int row = i * 64 + srow;
            GLDS(Abase + (size_t)(m0 + row) * 1024 + k0 + ske,
                 As + i * 2048 + w * 512);
            GLDS(Btbase + (size_t)row * 1024 + k0 + ske,
                 Bs + i * 2048 + w * 512);
        }
        __syncthreads();

        s16x8 af[4], bf[4];
#pragma unroll
        for (int ms = 0; ms < 4; ms++)
            af[ms] = *(const s16x8*)(As + (wm * 64 + ms * 16 + lc) * 32 + quad * 8);
#pragma unroll
        for (int ns = 0; ns < 4; ns++)
            bf[ns] = *(const s16x8*)(Bs + (wn * 64 + ns * 16 + lc) * 32 + quad * 8);
#pragma unroll
        for (int ms = 0; ms < 4; ms++)
#pragma unroll
            for (int ns = 0; ns < 4; ns++)
                acc[ms][ns] = __builtin_amdgcn_mfma_f32_16x16x32_bf16(
                    af[ms], bf[ns], acc[ms][ns], 0, 0, 0);
    }

    const float* biasp = (s == 0) ? bq : (s == 1) ? bk : bv;
    const float premul = (s == 0) ? SCALE : 1.0f;
    ushort_t* outp = (s == 0) ? qw : (s == 1) ? kw : vw;

#pragma unroll
    for (int ns = 0; ns < 4; ns++) {
        const int nl = nsec0 + wn * 64 + ns * 16 + lc;
        const float bias = biasp[nl];
        const int h_ = nl >> 6, d_ = nl & 63;
#pragma unroll
        for (int ms = 0; ms < 4; ms++) {
#pragma unroll
            for (int r = 0; r < 4; r++) {
                int m = m0 + wm * 64 + ms * 16 + quad * 4 + r;
                float val = (acc[ms][ns][r] + bias) * premul;
                int b_ = m >> 11, t_ = m & (T - 1);
                size_t bh = (size_t)(b_ * H + h_);
                outp[((bh * T + t_) << 6) + d_] = f2bf(val);
            }
        }
    }
}

// ---------------------------------------------------------------------------
// Final projection: out = o(4096x1024)bf16 @ Wot^T + bo, fp32 out.
// ---------------------------------------------------------------------------
__global__ __launch_bounds__(256) void gemm_final(
    const ushort_t* __restrict__ A, const ushort_t* __restrict__ Wot,
    const float* __restrict__ bo, float* __restrict__ out)
{
    __shared__ ushort_t As[128 * 32];
    __shared__ ushort_t Bs[128 * 32];

    const int tid = threadIdx.x;
    const int w = tid >> 6, lane = tid & 63;
    const int quad = lane >> 4, lc = lane & 15;
    const int wm = w & 1, wn = w >> 1;

    const int n0 = blockIdx.x * 128;
    const int m0 = blockIdx.y * 128;

    const int srow = (w << 4) + (lane >> 2);
    const int ske  = (lane & 3) * 8;

    fv4 acc[4][4] = {};

    for (int k0 = 0; k0 < 1024; k0 += 32) {
        __syncthreads();
#pragma unroll
        for (int i = 0; i < 2; i++) {
            int row = i * 64 + srow;
            GLDS(A + (size_t)(m0 + row) * 1024 + k0 + ske,
                 As + i * 2048 + w * 512);
            GLDS(Wot + (size_t)(n0 + row) * 1024 + k0 + ske,
                 Bs + i * 2048 + w * 512);
        }
        __syncthreads();

        s16x8 af[4], bf[4];
#pragma unroll
        for (int ms = 0; ms < 4; ms++)
            af[ms] = *(const s16x8*)(As + (wm * 64 + ms * 16 + lc) * 32 + quad * 8);
#pragma unroll
        for (int ns = 0; ns < 4; ns++)
            bf[ns] = *(const s16x8*)(Bs + (wn * 64 + ns * 16 + lc) * 32 + quad * 8);
#pragma unroll
        for (int ms = 0; ms < 4; ms++)
#pragma unroll
            for (int ns = 0; ns < 4; ns++)
                acc[ms][ns] = __builtin_amdgcn_mfma_f32_16x16x32_bf16(
                    af[ms], bf[ns], acc[ms][ns], 0, 0, 0);
    }

#pragma unroll
    for (int ns = 0; ns < 4; ns++) {
        const int n = n0 + wn * 64 + ns * 16 + lc;
        const float bias = bo[n];
#pragma unroll
        for (int ms = 0; ms < 4; ms++) {
#pragma unroll
            for (int r = 0; r < 4; r++) {
                int m = m0 + wm * 64 + ms * 16 + quad * 4 + r;
                out[(size_t)m * 1024 + n] = acc[ms][ns][r] + bias;
            }
        }
    }
}

// ---------------------------------------------------------------------------
// Flash attention v2 — S^T orientation.
// S^T = K @ Q^T  (C-layout: [key=quad*4+r][q=lane&15]) -> per-lane softmax
// stats (2 shfls/tile instead of 32). O^T = V^T @ P^T.
// Block: 256 thr = 4 waves; 128 q-rows/block (32/wave as 2 q-tiles of 16).
// K-tile 64. ps strips are wave-private (no barrier for P round-trip).
// ---------------------------------------------------------------------------
__global__ __launch_bounds__(256) void attn(
    const ushort_t* __restrict__ q, const ushort_t* __restrict__ k,
    const ushort_t* __restrict__ vT, ushort_t* __restrict__ o)
{
    __shared__ ushort_t ks[64][72];     // [key][d]
    __shared__ ushort_t vsT[64][72];    // [vd][key]
    __shared__ ushort_t ps[4][32][72];  // per-wave [q][key] P^T staging

    const int tid = threadIdx.x;
    const int w = tid >> 6, lane = tid & 63;
    const int quad = lane >> 4, lc = lane & 15;
    const int qt = blockIdx.x;   // 0..15 (128 q-rows each)
    const int bh = blockIdx.y;   // 0..31

    // hoisted Q B-frags, loaded directly from global: B[k=d=quad*8+j][n=q=lc]
    s16x8 aq[2][2];
    const ushort_t* qb = q + ((size_t)bh * T + qt * 128 + w * 32) * D;
#pragma unroll
    for (int j = 0; j < 2; j++)
#pragma unroll
        for (int h = 0; h < 2; h++)
            aq[j][h] = *(const s16x8*)(qb + (size_t)(j * 16 + lc) * D + h * 32 + quad * 8);

    fv4 accO[2][4] = {};   // accO[qtile][vd-tile] : [vd=quad*4+r][q=lc]
    float mrun[2] = {-1e30f, -1e30f}, lrun[2] = {0.f, 0.f};

    const ushort_t* kb0 = k + (size_t)bh * T * D;
    const ushort_t* vb0 = vT + (size_t)bh * D * T;

    const int srow = tid >> 2;          // 0..63
    const int sc   = (tid & 3) * 16;    // 0,16,32,48

    for (int kt = 0; kt < T / 64; kt++) {
        __syncthreads();   // all waves done reading prev ks/vsT
        {
            const ushort_t* kp = kb0 + (size_t)(kt * 64 + srow) * D + sc;
            const ushort_t* vp = vb0 + (size_t)srow * T + kt * 64 + sc;
            s16x8 a0 = *(const s16x8*)kp;
            s16x8 a1 = *(const s16x8*)(kp + 8);
            s16x8 b0 = *(const s16x8*)vp;
            s16x8 b1 = *(const s16x8*)(vp + 8);
            *(s16x8*)&ks[srow][sc] = a0;
            *(s16x8*)&ks[srow][sc + 8] = a1;
            *(s16x8*)&vsT[srow][sc] = b0;
            *(s16x8*)&vsT[srow][sc + 8] = b1;
        }
        __syncthreads();

        // S^T = K @ Q^T : accST[qtile][key-tile]
        fv4 accST[2][4] = {};
#pragma unroll
        for (int t4 = 0; t4 < 4; t4++) {
            s16x8 ak0 = *(const s16x8*)&ks[t4 * 16 + lc][quad * 8];
            s16x8 ak1 = *(const s16x8*)&ks[t4 * 16 + lc][32 + quad * 8];
#pragma unroll
            for (int j = 0; j < 2; j++) {
                accST[j][t4] = __builtin_amdgcn_mfma_f32_16x16x32_bf16(
                    ak0, aq[j][0], accST[j][t4], 0, 0, 0);
                accST[j][t4] = __builtin_amdgcn_mfma_f32_16x16x32_bf16(
                    ak1, aq[j][1], accST[j][t4], 0, 0, 0);
            }
        }

        // online softmax: per lane, q = (qtile)*16 + lc; keys of this quad are
        // in-register; combine quads with 2 shfls.
#pragma unroll
        for (int j = 0; j < 2; j++) {
            float mx = -1e30f;
#pragma unroll
            for (int t4 = 0; t4 < 4; t4++)
#pragma unroll
                for (int r = 0; r < 4; r++)
                    mx = fmaxf(mx, accST[j][t4][r]);
            mx = fmaxf(mx, __shfl_xor(mx, 16));
            mx = fmaxf(mx, __shfl_xor(mx, 32));
            float mnew = fmaxf(mrun[j], mx);
            float alpha = __expf(mrun[j] - mnew);
            float psum = 0.f;
#pragma unroll
            for (int t4 = 0; t4 < 4; t4++)
#pragma unroll
                for (int r = 0; r < 4; r++) {
                    float p = __expf(accST[j][t4][r] - mnew);
                    ps[w][j * 16 + lc][t4 * 16 + quad * 4 + r] = f2bf(p);
                    psum += p;
                }
            psum += __shfl_xor(psum, 16);
            psum += __shfl_xor(psum, 32);
            lrun[j] = lrun[j] * alpha + psum;
            mrun[j] = mnew;
#pragma unroll
            for (int t4 = 0; t4 < 4; t4++)
#pragma unroll
                for (int r = 0; r < 4; r++)
                    accO[j][t4][r] *= alpha;
        }

        // P^T B-frags from wave-private ps (same-wave lgkmcnt ordering, no barrier)
        s16x8 pb[2][2];
#pragma unroll
        for (int j = 0; j < 2; j++)
#pragma unroll
            for (int g = 0; g < 2; g++)
                pb[j][g] = *(const s16x8*)&ps[w][j * 16 + lc][g * 32 + quad * 8];

        // O^T += V^T @ P^T
#pragma unroll
        for (int t4 = 0; t4 < 4; t4++)
#pragma unroll
            for (int g = 0; g < 2; g++) {
                s16x8 av = *(const s16x8*)&vsT[t4 * 16 + lc][g * 32 + quad * 8];
#pragma unroll
                for (int j = 0; j < 2; j++)
                    accO[j][t4] = __builtin_amdgcn_mfma_f32_16x16x32_bf16(
                        av, pb[j][g], accO[j][t4], 0, 0, 0);
            }
    }

    // epilogue: normalize, write (B, T, H*64) bf16. Lane owns one q-row.
    const int b_ = bh >> 4, h_ = bh & 15;
#pragma unroll
    for (int j = 0; j < 2; j++) {
        float inv = 1.0f / lrun[j];
        int row = qt * 128 + w * 32 + j * 16 + lc;
        ushort_t* op = o + ((size_t)b_ * T + row) * C + h_ * 64;
#pragma unroll
        for (int t4 = 0; t4 < 4; t4++) {
            union { s16x4 v; ushort_t u[4]; } u;
#pragma unroll
            for (int r = 0; r < 4; r++) u.u[r] = f2bf(accO[j][t4][r] * inv);
            *(s16x4*)(op + t4 * 16 + quad * 4) = u.v;
        }
    }
}

// ---------------------------------------------------------------------------
extern "C" void kernel_launch(void* const* d_in, const int* in_sizes, int n_in,
                              void* d_out, int out_size, void* d_ws, size_t ws_size,
                              hipStream_t stream)
{
    const float* Q  = (const float*)d_in[0];
    const float* K  = (const float*)d_in[1];
    const float* V  = (const float*)d_in[2];
    const float* Wq = (const float*)d_in[3];
    const float* bq = (const float*)d_in[4];
    const float* Wk = (const float*)d_in[5];
    const float* bk = (const float*)d_in[6];
    const float* Wv = (const float*)d_in[7];
    const float* bv = (const float*)d_in[8];
    const float* Wo = (const float*)d_in[9];
    const float* bo = (const float*)d_in[10];
    float* out = (float*)d_out;

    // ws: qkvbf 25.2MB (reused as ow after gemm_qkv) | Wt 8.4 | qw 8.4 | kw 8.4
    //     | vw 8.4 | vt 8.4  = 67.2MB total
    ushort_t* qkvbf = (ushort_t*)d_ws;
    ushort_t* Wt = qkvbf + (size_t)3 * M * C;
    ushort_t* qw = Wt + (size_t)4096 * 1024;
    ushort_t* kw = qw + (size_t)M * C;
    ushort_t* vw = kw + (size_t)M * C;
    ushort_t* vt = vw + (size_t)M * C;
    ushort_t* ow = qkvbf;                      // alias: qkv bf16 dead after gemm_qkv
    ushort_t* Wot = Wt + (size_t)3072 * 1024;

    dim3 blk(256);
    convert_qkv<<<dim3(3 * M * C / 2048), blk, 0, stream>>>(Q, K, V, qkvbf);
    transpose_w<<<dim3(16, 16, 4), blk, 0, stream>>>(Wq, Wk, Wv, Wo, Wt);
    gemm_qkv<<<dim3(24, 32), blk, 0, stream>>>(qkvbf, Wt, bq, bk, bv, qw, kw, vw);
    transpose_v<<<dim3(T / 64, B * H), blk, 0, stream>>>(vw, vt);
    attn<<<dim3(T / 128, B * H), blk, 0, stream>>>(qw, kw, vt, ow);
    gemm_final<<<dim3(8, 32), blk, 0, stream>>>(ow, Wot, bo, out);
}